// Round 9
// baseline (296.908 us; speedup 1.0000x reference)
//
#include <hip/hip_runtime.h>
#include <math.h>

#define B  128
#define L  64
#define NS 32
#define NI 16
#define D  256

typedef __attribute__((ext_vector_type(8))) short bf16x8;
typedef __attribute__((ext_vector_type(4))) float f32x4;

__device__ __forceinline__ float wave_reduce_sum(float v) {
#pragma unroll
  for (int off = 32; off; off >>= 1) v += __shfl_xor(v, off, 64);
  return v;
}
__device__ __forceinline__ float wave_reduce_max(float v) {
#pragma unroll
  for (int off = 32; off; off >>= 1) v = fmaxf(v, __shfl_xor(v, off, 64));
  return v;
}

// packed RTNE f32x2 -> bf16x2 (single HW instr)
__device__ __forceinline__ uint cvt_pk_bf16(float a, float b) {
  uint r;
  asm("v_cvt_pk_bf16_f32 %0, %1, %2" : "=v"(r) : "v"(a), "v"(b));
  return r;  // lo16 = bf16(a), hi16 = bf16(b)
}
// float4 -> hi-pair u32x2 + lo-pair u32x2 (x ~= hi + lo, residual ~2^-17)
__device__ __forceinline__ void split4(float4 v, uint2& h, uint2& lo) {
  h.x = cvt_pk_bf16(v.x, v.y);
  h.y = cvt_pk_bf16(v.z, v.w);
  float h0 = __uint_as_float(h.x << 16);
  float h1 = __uint_as_float(h.x & 0xFFFF0000u);
  float h2 = __uint_as_float(h.y << 16);
  float h3 = __uint_as_float(h.y & 0xFFFF0000u);
  lo.x = cvt_pk_bf16(v.x - h0, v.y - h1);
  lo.y = cvt_pk_bf16(v.z - h2, v.w - h3);
}

// async global->LDS DMA, 16B per lane (wave-uniform LDS base + lane*16;
// GLOBAL source is per-lane)
__device__ __forceinline__ void dma16(const void* g, void* l) {
  __builtin_amdgcn_global_load_lds(
      (const __attribute__((address_space(1))) void*)g,
      (__attribute__((address_space(3))) void*)l, 16, 0, 0);
}

// swizzled ushort index into a [row][64 k] bf16 tile (128B rows).
// XOR (row&7)<<4 within-row: b128 reads bank-spread; used both by the
// image precompute (kx_split) and the LDS reader.
__device__ __forceinline__ int swzA(int row, int kcol) {
  int byte = (row << 7) + (kcol << 1);
  byte ^= (row & 7) << 4;
  return byte >> 1;
}

// ---------------------------------------------------------------------------
// KX: precompute swizzled bf16 hi/lo images of tf.
// Tile (l, jci): [128 b][64 k], k = jci*64 + 0..63.  16KB per image tile.
// ---------------------------------------------------------------------------
__global__ __launch_bounds__(256) void kx_split(
    const float* __restrict__ tf, ushort* __restrict__ xh,
    ushort* __restrict__ xl) {
  int tile = blockIdx.x;          // l*4 + jci
  int l  = tile >> 2;
  int jc = (tile & 3) * 64;
  int t  = threadIdx.x;
  int row = t >> 1;               // b
  int k0  = (t & 1) * 32;
  const float* src = tf + ((size_t)row * L + l) * D + jc + k0;
  ushort* ht = xh + (size_t)tile * 8192;
  ushort* lt = xl + (size_t)tile * 8192;
#pragma unroll
  for (int c = 0; c < 8; ++c) {
    float4 v = *(const float4*)(src + c * 4);
    uint2 h, lo;
    split4(v, h, lo);
    int ix = swzA(row, k0 + c * 4);
    *(uint2*)&ht[ix] = h;
    *(uint2*)&lt[ix] = lo;
  }
}

// ---------------------------------------------------------------------------
// K1: per (b,l): a_words = mean(x); logits = w_route_ws[l] . x; softmax;
//     wlsT[l][s][b] = c_ws * a_words.
// ---------------------------------------------------------------------------
__global__ __launch_bounds__(256) void k1_route_words(
    const float* __restrict__ tf, const float* __restrict__ wr,
    float* __restrict__ wlsT, float* __restrict__ a_words) {
  int bl = blockIdx.x;
  int b  = bl >> 6;
  int l  = bl & (L - 1);
  int t  = threadIdx.x;
  int wave = t >> 6, lane = t & 63;
  __shared__ float sx[D];
  __shared__ float slog[NS];
  __shared__ float s_aw;
  sx[t] = tf[bl * D + t];
  __syncthreads();
  const float* wbase = wr + l * NS * D;
#pragma unroll
  for (int r = 0; r < 8; ++r) {
    int n = wave * 8 + r;
    const float* w = wbase + n * D;
    float p = 0.f;
#pragma unroll
    for (int jj = 0; jj < 4; ++jj) {
      int j = lane + jj * 64;
      p = fmaf(w[j], sx[j], p);
    }
    p = wave_reduce_sum(p);
    if (lane == 0) slog[n] = p;
  }
  if (wave == 0) {
    float p = sx[lane] + sx[lane + 64] + sx[lane + 128] + sx[lane + 192];
    p = wave_reduce_sum(p);
    if (lane == 0) s_aw = p * (1.f / D);
  }
  __syncthreads();
  if (wave == 0) {
    float aw = s_aw;
    float v = (lane < NS) ? slog[lane] : -INFINITY;
    float m = wave_reduce_max(v);
    float e = (lane < NS) ? __expf(v - m) : 0.f;
    float s = wave_reduce_sum(e);
    if (lane < NS) wlsT[(l * NS + lane) * B + b] = (e / s) * aw;
    if (lane == 0) a_words[bl] = aw;
  }
}

// ---------------------------------------------------------------------------
// K2: weighted_c[b,s] = sum_l wlsT[l][s][b]; a_slots = wc / sum_l a_words.
// ---------------------------------------------------------------------------
__global__ __launch_bounds__(64) void k2_slots_agg(
    const float* __restrict__ wlsT, const float* __restrict__ a_words,
    float* __restrict__ weighted_c, float* __restrict__ a_slots) {
  int b = blockIdx.x;
  int lane = threadIdx.x;
  float aw = a_words[b * L + lane];
  float sa = wave_reduce_sum(aw);
  if (lane < NS) {
    float wc = 0.f;
    for (int l = 0; l < L; ++l) wc += wlsT[(l * NS + lane) * B + b];
    weighted_c[b * NS + lane] = wc;
    a_slots[b * NS + lane] = wc / sa;
  }
}

// ---------------------------------------------------------------------------
// K3 v5: counted-vmcnt double-buffered DMA pipeline (never drains to 0).
// Per block (sp, s, it in 4, bh in 2):
//   R[b_local, i] = sum_l sw[b] * (sum_j W[l,s,i0+i,j] * x_split[bh*64+b, j])
// A: pre-split/pre-swizzled bf16 hi/lo images -> DMA (4/wave/step).
// W: f32 via DMA with per-lane SOURCE swizzle (4/wave/step) -> LDS -> reg
//    split.  Loop has ZERO other VMEM => vmcnt(8) is exact.
// b-half pairs share a W tile; bx = chunk*16 + bh*8 + xcd co-locates the
// pair on one XCD so the 2nd W read hits L2/L3.
// 3-term emulated fp32: Ah*Bh + Ah*Bl + Al*Bh.
// ---------------------------------------------------------------------------
__global__ __launch_bounds__(256, 2) void k3_mfma(
    const ushort* __restrict__ xh, const ushort* __restrict__ xl,
    const float* __restrict__ wp, const float* __restrict__ wlsT,
    float* __restrict__ part, int nsplit) {
  __shared__ ushort Ah[2][4096], Al[2][4096];  // 8KB per buf each
  __shared__ float  Wt[2][4096];               // 16KB per buf
  __shared__ float  swl[4096];                 // wls scales, whole chunk

  int bx    = blockIdx.x;
  int xcd   = bx & 7;
  int bh    = (bx >> 3) & 1;
  int chunk = bx >> 4;
  int pidx  = chunk * 8 + xcd;
  int sp = pidx % nsplit;
  int rr = pidx / nsplit;
  int it = rr & 3, s = rr >> 2;
  int i0 = it * 64;
  int lchunk = L / nsplit, l0 = sp * lchunk;
  int steps  = lchunk * 4;

  int t = threadIdx.x, lane = t & 63, wv = t >> 6;
  int fr = lane & 15, q = lane >> 4;

  // per-lane invariant W-DMA source offsets (bytes within a step's W tile)
  int wofs[4];
#pragma unroll
  for (int wi = 0; wi < 4; ++wi) {
    int row  = (wv * 4 + wi) * 4 + (lane >> 4);
    int soff = ((lane & 15) * 16) ^ ((row & 7) << 4);
    wofs[wi] = row * 1024 + soff;  // row stride = D*4 = 1024B
  }
  int aofs = wv * 1024 + lane * 8;  // ushort units (2 chunks of 512)

  // preload all wls scales for this (chunk, b-half) into LDS
  for (int of = t; of < lchunk * 64; of += 256) {
    int li = of >> 6, b = of & 63;
    swl[of] = wlsT[((size_t)(l0 + li) * NS + s) * B + bh * 64 + b];
  }
  asm volatile("s_waitcnt vmcnt(0) lgkmcnt(0)" ::: "memory");
  __builtin_amdgcn_s_barrier();

  f32x4 P[4], R[4];
#pragma unroll
  for (int mi = 0; mi < 4; ++mi) { P[mi] = (f32x4)0.f; R[mi] = (f32x4)0.f; }

  auto issue = [&](int step) {            // 8 DMA instructions per wave
    int cs = step < steps ? step : steps - 1;
    int pb = step & 1;
    int l = l0 + (cs >> 2), jci = cs & 3;
    size_t tile = ((size_t)l * 4 + jci) * 8192 + (size_t)bh * 4096;
    const ushort* th = xh + tile;
    const ushort* tl = xl + tile;
    dma16(th + aofs,       &Ah[pb][wv * 1024]);
    dma16(th + aofs + 512, &Ah[pb][wv * 1024 + 512]);
    dma16(tl + aofs,       &Al[pb][wv * 1024]);
    dma16(tl + aofs + 512, &Al[pb][wv * 1024 + 512]);
    const char* wbase = (const char*)(wp + ((size_t)l * NS + s) * (D * D) +
                                      (size_t)i0 * D + jci * 64);
#pragma unroll
    for (int wi = 0; wi < 4; ++wi)
      dma16(wbase + wofs[wi], (char*)&Wt[pb][0] + (wv * 4 + wi) * 1024);
  };

  issue(0);
  for (int step = 0; step < steps; ++step) {
    issue(step + 1);
    asm volatile("s_waitcnt vmcnt(8)" ::: "memory");  // step's 8 done; next 8 in flight
    __builtin_amdgcn_s_barrier();
    int pb = step & 1;
    // ---- W fragment: LDS f32 (swizzled) -> reg -> hi/lo bf16 split ----
    int wrow = wv * 16 + fr;
    int wkey = (wrow & 7) << 4;
    const char* wb = (const char*)&Wt[pb][0];
    bf16x8 fh[2], fl[2];
#pragma unroll
    for (int k2 = 0; k2 < 2; ++k2) {
      int base = wrow * 256 + k2 * 128 + q * 32;
      float4 w0 = *(const float4*)(wb + ((base) ^ wkey));
      float4 w1 = *(const float4*)(wb + ((base + 16) ^ wkey));
      uint2 h0, e0, h1, e1;
      split4(w0, h0, e0);
      split4(w1, h1, e1);
      uint4 hu = {h0.x, h0.y, h1.x, h1.y};
      uint4 lu = {e0.x, e0.y, e1.x, e1.y};
      fh[k2] = __builtin_bit_cast(bf16x8, hu);
      fl[k2] = __builtin_bit_cast(bf16x8, lu);
    }
    // ---- MFMA: 3-term emulated fp32 into per-l accumulator P ----
#pragma unroll
    for (int k2 = 0; k2 < 2; ++k2) {
#pragma unroll
      for (int mi = 0; mi < 4; ++mi) {
        int arow  = mi * 16 + fr;
        int abyte = (arow * 128 + (k2 * 32 + q * 8) * 2) ^ ((arow & 7) << 4);
        bf16x8 ah = *(const bf16x8*)((const char*)&Ah[pb][0] + abyte);
        bf16x8 al = *(const bf16x8*)((const char*)&Al[pb][0] + abyte);
        P[mi] = __builtin_amdgcn_mfma_f32_16x16x32_bf16(ah, fh[k2], P[mi], 0, 0, 0);
        P[mi] = __builtin_amdgcn_mfma_f32_16x16x32_bf16(ah, fl[k2], P[mi], 0, 0, 0);
        P[mi] = __builtin_amdgcn_mfma_f32_16x16x32_bf16(al, fh[k2], P[mi], 0, 0, 0);
      }
    }
    // ---- per-l scale fold: R += sw[b]*P (fp32) ----
    if ((step & 3) == 3) {
      int sl = step >> 2;
#pragma unroll
      for (int mi = 0; mi < 4; ++mi) {
        f32x4 s4 = *(const f32x4*)&swl[sl * 64 + mi * 16 + q * 4];
        R[mi] += s4 * P[mi];
        P[mi] = (f32x4)0.f;
      }
    }
    asm volatile("s_waitcnt lgkmcnt(0)" ::: "memory");  // LDS reads done
    __builtin_amdgcn_s_barrier();                       // before next overwrite
  }

  // ---- epilogue: write partials ----
  float* pout = part + ((size_t)sp * NS + s) * (B * D);
  int col = i0 + wv * 16 + fr;
#pragma unroll
  for (int mi = 0; mi < 4; ++mi)
#pragma unroll
    for (int e = 0; e < 4; ++e) {
      int bb = bh * 64 + mi * 16 + q * 4 + e;
      pout[(size_t)bb * D + col] = R[mi][e];
    }
}

// ---------------------------------------------------------------------------
// K3R: u_slots[b,s,i] = (sum_sp part[sp,s,b,i]) / weighted_c[b,s]
// ---------------------------------------------------------------------------
__global__ __launch_bounds__(256) void k3r_reduce(
    const float* __restrict__ part, const float* __restrict__ wc,
    float* __restrict__ u_slots, int nsplit) {
  int idx = blockIdx.x * 256 + threadIdx.x;  // over (s,b,i)
  int i  = idx & (D - 1);
  int sb = idx >> 8;
  int b  = sb & (B - 1);
  int s  = sb >> 7;
  float v = 0.f;
  for (int sp = 0; sp < nsplit; ++sp)
    v += part[(size_t)sp * (NS * B * D) + idx];
  u_slots[((size_t)b * NS + s) * D + i] = v / wc[b * NS + s];
}

// ---------------------------------------------------------------------------
// K4: per (b,s): logits2 = w_route_si[s] . u_slots[b,s]; softmax over NI;
//     w2 = c_si * a_slots.
// ---------------------------------------------------------------------------
__global__ __launch_bounds__(64) void k4_route_si(
    const float* __restrict__ u_slots, const float* __restrict__ wr_si,
    const float* __restrict__ a_slots, float* __restrict__ w2) {
  int bs = blockIdx.x;
  int s  = bs & (NS - 1);
  int lane = threadIdx.x;
  __shared__ float su[D];
  __shared__ float slog[NI];
#pragma unroll
  for (int jj = 0; jj < 4; ++jj) su[lane + jj * 64] = u_slots[bs * D + lane + jj * 64];
  __syncthreads();
  for (int i = 0; i < NI; ++i) {
    const float* w = wr_si + (s * NI + i) * D;
    float p = 0.f;
#pragma unroll
    for (int jj = 0; jj < 4; ++jj) {
      int j = lane + jj * 64;
      p = fmaf(w[j], su[j], p);
    }
    p = wave_reduce_sum(p);
    if (lane == 0) slog[i] = p;
  }
  __syncthreads();
  float v = (lane < NI) ? slog[lane] : -INFINITY;
  float m = wave_reduce_max(v);
  float e = (lane < NI) ? __expf(v - m) : 0.f;
  float ssum = wave_reduce_sum(e);
  if (lane < NI) w2[bs * NI + lane] = (e / ssum) * a_slots[bs];
}

// ---------------------------------------------------------------------------
// K5: wc2[b,i] = sum_s w2; a_intents = wc2 / sum_s a_slots.
// ---------------------------------------------------------------------------
__global__ __launch_bounds__(64) void k5_intents_agg(
    const float* __restrict__ w2, const float* __restrict__ a_slots,
    float* __restrict__ wc2, float* __restrict__ a_intents) {
  int b = blockIdx.x;
  int lane = threadIdx.x;
  float as = (lane < NS) ? a_slots[b * NS + lane] : 0.f;
  float sas = wave_reduce_sum(as);
  if (lane < NI) {
    float wc = 0.f;
    for (int s = 0; s < NS; ++s) wc += w2[(b * NS + s) * NI + lane];
    wc2[b * NI + lane] = wc;
    a_intents[b * NI + lane] = wc / sas;
  }
}

// ---------------------------------------------------------------------------
// K6: Wsum[s,i,k] = sum_j w_pose_si[s,i,j,k] (float4-vectorized over k).
// ---------------------------------------------------------------------------
__global__ __launch_bounds__(256) void k6_wsum(
    const float* __restrict__ wps, float* __restrict__ wsum) {
  __shared__ float red[4][D];
  int si = blockIdx.x;
  int t  = threadIdx.x;
  int k4 = (t & 63) * 4;
  int jg = t >> 6;
  const float* base = wps + (size_t)si * D * D;
  float4 acc = {0.f, 0.f, 0.f, 0.f};
  for (int j = jg; j < D; j += 4) {
    float4 v = *(const float4*)(base + (size_t)j * D + k4);
    acc.x += v.x; acc.y += v.y; acc.z += v.z; acc.w += v.w;
  }
  *(float4*)&red[jg][k4] = acc;
  __syncthreads();
  wsum[si * D + t] = (red[0][t] + red[1][t]) + (red[2][t] + red[3][t]);
}

// ---------------------------------------------------------------------------
// K7: u_intents[b,i,k] = sum_s w2[b,s,i]*u_slots[b,s,k]*Wsum[s,i,k] / wc2[b,i]
// ---------------------------------------------------------------------------
__global__ __launch_bounds__(256) void k7_uintents(
    const float* __restrict__ u_slots, const float* __restrict__ w2,
    const float* __restrict__ wsum, const float* __restrict__ wc2,
    float* __restrict__ u_intents) {
  int bi = blockIdx.x;
  int b = bi >> 4, i = bi & (NI - 1);
  int k = threadIdx.x;
  float acc = 0.f;
  for (int s = 0; s < NS; ++s) {
    float w = w2[(b * NS + s) * NI + i];
    acc = fmaf(w * u_slots[(b * NS + s) * D + k], wsum[(s * NI + i) * D + k], acc);
  }
  u_intents[bi * D + k] = acc / wc2[bi];
}

// ---------------------------------------------------------------------------
extern "C" void kernel_launch(void* const* d_in, const int* in_sizes, int n_in,
                              void* d_out, int out_size, void* d_ws, size_t ws_size,
                              hipStream_t stream) {
  const float* tf    = (const float*)d_in[0];  // (B,L,D)
  const float* wr_ws = (const float*)d_in[1];  // (L,NS,D)
  const float* wp_ws = (const float*)d_in[2];  // (L,NS,D,D)
  const float* wr_si = (const float*)d_in[3];  // (NS,NI,D)
  const float* wp_si = (const float*)d_in[4];  // (NS,NI,D,D)

  float* out       = (float*)d_out;
  float* a_slots   = out;                      // B*NS
  float* u_slots   = a_slots + B * NS;         // B*NS*D
  float* a_intents = u_slots + B * NS * D;     // B*NI
  float* u_intents = a_intents + B * NI;       // B*NI*D

  float* ws         = (float*)d_ws;
  float* wlsT       = ws;                      // L*NS*B  = 262144
  float* a_words    = wlsT + L * NS * B;       // B*L     = 8192
  float* weighted_c = a_words + B * L;         // B*NS    = 4096
  float* w2         = weighted_c + B * NS;     // B*NS*NI = 65536
  float* wc2        = w2 + B * NS * NI;        // B*NI    = 2048
  float* wsum       = wc2 + B * NI;            // NS*NI*D = 131072
  // bf16 hi/lo swizzled images of tf: 64*4 tiles x 8192 ushorts each
  ushort* xh        = (ushort*)(wsum + NS * NI * D);       // 2,097,152 ushorts
  ushort* xl        = xh + (size_t)L * 4 * 8192;           // 2,097,152 ushorts
  float*  part      = (float*)(xl + (size_t)L * 4 * 8192); // nsplit*NS*B*D

  const size_t base_f  = 473088 + 2097152;     // floats incl. images
  const size_t chunk_f = (size_t)NS * B * D;   // 1,048,576 per split
  size_t avail_f = ws_size / sizeof(float);
  int nsplit = 1;
  if (avail_f >= base_f + 4 * chunk_f)      nsplit = 4;
  else if (avail_f >= base_f + 2 * chunk_f) nsplit = 2;

  kx_split<<<L * 4, 256, 0, stream>>>(tf, xh, xl);
  k1_route_words<<<B * L, 256, 0, stream>>>(tf, wr_ws, wlsT, a_words);
  k2_slots_agg<<<B, 64, 0, stream>>>(wlsT, a_words, weighted_c, a_slots);
  // grid: 32 s x 4 i-tiles x 2 b-halves x nsplit, pair-on-XCD encoding
  k3_mfma<<<NS * 4 * 2 * nsplit, 256, 0, stream>>>(xh, xl, wp_ws, wlsT, part, nsplit);
  k3r_reduce<<<(NS * B * D) / 256, 256, 0, stream>>>(part, weighted_c, u_slots, nsplit);
  k6_wsum<<<NS * NI, 256, 0, stream>>>(wp_si, wsum);
  k4_route_si<<<B * NS, 64, 0, stream>>>(u_slots, wr_si, a_slots, w2);
  k5_intents_agg<<<B, 64, 0, stream>>>(w2, a_slots, wc2, a_intents);
  k7_uintents<<<B * NI, 256, 0, stream>>>(u_slots, w2, wsum, wc2, u_intents);
}

// Round 10
// 244.404 us; speedup vs baseline: 1.2148x; 1.2148x over previous
//
#include <hip/hip_runtime.h>
#include <math.h>

#define B  128
#define L  64
#define NS 32
#define NI 16
#define D  256

typedef __attribute__((ext_vector_type(8))) short bf16x8;
typedef __attribute__((ext_vector_type(4))) float f32x4;

__device__ __forceinline__ float wave_reduce_sum(float v) {
#pragma unroll
  for (int off = 32; off; off >>= 1) v += __shfl_xor(v, off, 64);
  return v;
}
__device__ __forceinline__ float wave_reduce_max(float v) {
#pragma unroll
  for (int off = 32; off; off >>= 1) v = fmaxf(v, __shfl_xor(v, off, 64));
  return v;
}

// packed RTNE f32x2 -> bf16x2 (single HW instr)
__device__ __forceinline__ uint cvt_pk_bf16(float a, float b) {
  uint r;
  asm("v_cvt_pk_bf16_f32 %0, %1, %2" : "=v"(r) : "v"(a), "v"(b));
  return r;  // lo16 = bf16(a), hi16 = bf16(b)
}
// float4 -> hi-pair u32x2 + lo-pair u32x2 (x ~= hi + lo, residual ~2^-17)
__device__ __forceinline__ void split4(float4 v, uint2& h, uint2& lo) {
  h.x = cvt_pk_bf16(v.x, v.y);
  h.y = cvt_pk_bf16(v.z, v.w);
  float h0 = __uint_as_float(h.x << 16);
  float h1 = __uint_as_float(h.x & 0xFFFF0000u);
  float h2 = __uint_as_float(h.y << 16);
  float h3 = __uint_as_float(h.y & 0xFFFF0000u);
  lo.x = cvt_pk_bf16(v.x - h0, v.y - h1);
  lo.y = cvt_pk_bf16(v.z - h2, v.w - h3);
}

// async global->LDS DMA, 16B/lane; LDS dest = wave-uniform base + lane*16,
// global src = per-lane pointer.
__device__ __forceinline__ void dma16(const void* g, void* l) {
  __builtin_amdgcn_global_load_lds(
      (const __attribute__((address_space(1))) void*)g,
      (__attribute__((address_space(3))) void*)l, 16, 0, 0);
}

// ---------------------------------------------------------------------------
// KX: pre-split tf into bf16 hi/lo images, tiled [128 b][32 k] per (l,jc32),
// with (row&3) XOR on 16B units inside each 64B row  ->  k3's DMA is a pure
// linear copy and its ds_read_b128 pattern is bank-conflict-free.
// ---------------------------------------------------------------------------
__global__ __launch_bounds__(256) void kx_split(
    const float* __restrict__ tf, ushort* __restrict__ xh,
    ushort* __restrict__ xl) {
  int bx = blockIdx.x;            // l*4 + jp   (jp = 64-col pair)
  int l  = bx >> 2, jp = bx & 3;
  int t  = threadIdx.x;
  int row = t >> 1, sub = t & 1;
  int tile = bx * 2 + sub;        // l*8 + jc32-index
  const float* src = tf + ((size_t)row * L + l) * D + jp * 64 + sub * 32;
  ushort* ht = xh + (size_t)tile * 4096 + row * 32;
  ushort* lt = xl + (size_t)tile * 4096 + row * 32;
#pragma unroll
  for (int u = 0; u < 4; ++u) {
    float4 v0 = *(const float4*)(src + u * 8);
    float4 v1 = *(const float4*)(src + u * 8 + 4);
    uint2 h0, e0, h1, e1;
    split4(v0, h0, e0);
    split4(v1, h1, e1);
    int up = (u ^ (row & 3)) * 8;
    uint4 hu = {h0.x, h0.y, h1.x, h1.y};
    uint4 lu = {e0.x, e0.y, e1.x, e1.y};
    *(uint4*)&ht[up] = hu;
    *(uint4*)&lt[up] = lu;
  }
}

// ---------------------------------------------------------------------------
// K1: per (b,l): a_words = mean(x); logits = w_route_ws[l] . x; softmax;
//     wlsT[l][s][b] = c_ws * a_words.
// ---------------------------------------------------------------------------
__global__ __launch_bounds__(256) void k1_route_words(
    const float* __restrict__ tf, const float* __restrict__ wr,
    float* __restrict__ wlsT, float* __restrict__ a_words) {
  int bl = blockIdx.x;
  int b  = bl >> 6;
  int l  = bl & (L - 1);
  int t  = threadIdx.x;
  int wave = t >> 6, lane = t & 63;
  __shared__ float sx[D];
  __shared__ float slog[NS];
  __shared__ float s_aw;
  sx[t] = tf[bl * D + t];
  __syncthreads();
  const float* wbase = wr + l * NS * D;
#pragma unroll
  for (int r = 0; r < 8; ++r) {
    int n = wave * 8 + r;
    const float* w = wbase + n * D;
    float p = 0.f;
#pragma unroll
    for (int jj = 0; jj < 4; ++jj) {
      int j = lane + jj * 64;
      p = fmaf(w[j], sx[j], p);
    }
    p = wave_reduce_sum(p);
    if (lane == 0) slog[n] = p;
  }
  if (wave == 0) {
    float p = sx[lane] + sx[lane + 64] + sx[lane + 128] + sx[lane + 192];
    p = wave_reduce_sum(p);
    if (lane == 0) s_aw = p * (1.f / D);
  }
  __syncthreads();
  if (wave == 0) {
    float aw = s_aw;
    float v = (lane < NS) ? slog[lane] : -INFINITY;
    float m = wave_reduce_max(v);
    float e = (lane < NS) ? __expf(v - m) : 0.f;
    float s = wave_reduce_sum(e);
    if (lane < NS) wlsT[(l * NS + lane) * B + b] = (e / s) * aw;
    if (lane == 0) a_words[bl] = aw;
  }
}

// ---------------------------------------------------------------------------
// K2: weighted_c[b,s] = sum_l wlsT[l][s][b]; a_slots = wc / sum_l a_words.
// ---------------------------------------------------------------------------
__global__ __launch_bounds__(64) void k2_slots_agg(
    const float* __restrict__ wlsT, const float* __restrict__ a_words,
    float* __restrict__ weighted_c, float* __restrict__ a_slots) {
  int b = blockIdx.x;
  int lane = threadIdx.x;
  float aw = a_words[b * L + lane];
  float sa = wave_reduce_sum(aw);
  if (lane < NS) {
    float wc = 0.f;
    for (int l = 0; l < L; ++l) wc += wlsT[(l * NS + lane) * B + b];
    weighted_c[b * NS + lane] = wc;
    a_slots[b * NS + lane] = wc / sa;
  }
}

// ---------------------------------------------------------------------------
// K3 v6: W-once traffic-minimal DMA GEMM.
// Block (sp, s, ihalf): all 128 b x 128 i, l-chunk.  4 waves; each wave =
// 128 b x 32 i (mi=8 b-tiles, ni=2 i-tiles).  K-step 32.
// Per step per wave: 9 DMA (A-hi 2, A-lo 2, W 4, sw 1), exact vmcnt(9),
// double-buffered, 2 barriers/step.  W read ONCE from HBM (537MB total);
// A from L2 (8MB images).  3-term emulated fp32; per-l scale fold in f32.
// ---------------------------------------------------------------------------
__global__ __launch_bounds__(256, 2) void k3_mfma(
    const ushort* __restrict__ xh, const ushort* __restrict__ xl,
    const float* __restrict__ wp, const float* __restrict__ wlsT,
    float* __restrict__ part, int nsplit) {
  __shared__ ushort Ah[2][4096], Al[2][4096];  // [buf][128r x 32k swz] 8KB
  __shared__ float  Wt[2][4096];               // [buf][128r x 32k swz] 16KB
  __shared__ float  swl[2][256];               // per-l scales (dbuf)

  int bx  = blockIdx.x;
  int sp  = bx & (nsplit - 1);     // same-sp -> same XCD (bx%8 pattern)
  int rem = bx / nsplit;
  int ih  = rem & 1, s = rem >> 1;
  int i0  = ih * 128;
  int lchunk = L / nsplit, l0 = sp * lchunk;
  int steps  = lchunk * 8;

  int t = threadIdx.x, lane = t & 63, wv = t >> 6;
  int fr = lane & 15, q = lane >> 4;
  int wrow8 = lane >> 3;           // W-DMA row-within-instr (0..7)
  int wu    = lane & 7;            // W-DMA 16B unit
  int wswz  = ((wu ^ wrow8) << 4); // source swizzle (row&7 == wrow8)

  f32x4 P[8][2], R[8][2];
#pragma unroll
  for (int mi = 0; mi < 8; ++mi)
#pragma unroll
    for (int ni = 0; ni < 2; ++ni) { P[mi][ni] = (f32x4)0.f; R[mi][ni] = (f32x4)0.f; }

  auto issue = [&](int tn) {  // exactly 9 DMA per wave
    int cs = tn < steps ? tn : steps - 1;
    int pb = tn & 1;
    int li = cs >> 3, jci = cs & 7;
    int l  = l0 + li;
    const ushort* th = xh + ((size_t)l * 8 + jci) * 4096;
    const ushort* tl = xl + ((size_t)l * 8 + jci) * 4096;
    dma16(th + wv * 1024 + lane * 8,       &Ah[pb][wv * 1024]);
    dma16(th + wv * 1024 + 512 + lane * 8, &Ah[pb][wv * 1024 + 512]);
    dma16(tl + wv * 1024 + lane * 8,       &Al[pb][wv * 1024]);
    dma16(tl + wv * 1024 + 512 + lane * 8, &Al[pb][wv * 1024 + 512]);
    const char* wb = (const char*)wp +
                     (((size_t)l * NS + s) * (D * D) + (size_t)i0 * D) * 4 +
                     jci * 128;
#pragma unroll
    for (int wi = 0; wi < 4; ++wi) {
      int rbase = wv * 32 + wi * 8;
      dma16(wb + (size_t)(rbase + wrow8) * 1024 + wswz,
            (char*)&Wt[pb][0] + rbase * 128);
    }
    const char* sws = (const char*)(wlsT + ((size_t)l * NS + s) * B);
    dma16(sws + lane * 16, &swl[(cs >> 3) & 1][0]);
  };

  issue(0);
  for (int tt = 0; tt < steps; ++tt) {
    issue(tt + 1);
    asm volatile("s_waitcnt vmcnt(9)" ::: "memory");  // step tt landed; tt+1 in flight
    __builtin_amdgcn_s_barrier();
    int pb = tt & 1;
    // ---- W fragments: LDS f32 (swizzled) -> regs -> hi/lo bf16 ----
    bf16x8 fh[2], fl[2];
#pragma unroll
    for (int ni = 0; ni < 2; ++ni) {
      int wr = wv * 32 + ni * 16 + fr;
      const char* wbp = (const char*)&Wt[pb][0] + wr * 128;
      int key = fr & 7;
      float4 w0 = *(const float4*)(wbp + (((q * 2 + 0) ^ key) << 4));
      float4 w1 = *(const float4*)(wbp + (((q * 2 + 1) ^ key) << 4));
      uint2 h0, e0, h1, e1;
      split4(w0, h0, e0);
      split4(w1, h1, e1);
      uint4 hu = {h0.x, h0.y, h1.x, h1.y};
      uint4 lu = {e0.x, e0.y, e1.x, e1.y};
      fh[ni] = __builtin_bit_cast(bf16x8, hu);
      fl[ni] = __builtin_bit_cast(bf16x8, lu);
    }
    // ---- MFMA: 8 b-tiles x 2 i-tiles x 3 terms ----
#pragma unroll
    for (int mi = 0; mi < 8; ++mi) {
      int ar = mi * 16 + fr;
      int au = ar * 32 + ((q ^ (fr & 3)) << 3);
      bf16x8 ah = *(const bf16x8*)&Ah[pb][au];
      bf16x8 al = *(const bf16x8*)&Al[pb][au];
#pragma unroll
      for (int ni = 0; ni < 2; ++ni) {
        P[mi][ni] = __builtin_amdgcn_mfma_f32_16x16x32_bf16(ah, fh[ni], P[mi][ni], 0, 0, 0);
        P[mi][ni] = __builtin_amdgcn_mfma_f32_16x16x32_bf16(ah, fl[ni], P[mi][ni], 0, 0, 0);
        P[mi][ni] = __builtin_amdgcn_mfma_f32_16x16x32_bf16(al, fh[ni], P[mi][ni], 0, 0, 0);
      }
    }
    // ---- per-l fold: R += sw[b] * P (fp32) ----
    if ((tt & 7) == 7) {
      int lb = (tt >> 3) & 1;
#pragma unroll
      for (int mi = 0; mi < 8; ++mi) {
        f32x4 s4 = *(const f32x4*)&swl[lb][mi * 16 + q * 4];
#pragma unroll
        for (int ni = 0; ni < 2; ++ni) {
          R[mi][ni] += s4 * P[mi][ni];
          P[mi][ni] = (f32x4)0.f;
        }
      }
    }
    asm volatile("s_waitcnt lgkmcnt(0)" ::: "memory");  // all LDS reads done
    __builtin_amdgcn_s_barrier();                       // before buf overwrite
  }

  // ---- epilogue: write partials ----
  float* pout = part + ((size_t)sp * NS + s) * (B * D);
#pragma unroll
  for (int mi = 0; mi < 8; ++mi)
#pragma unroll
    for (int ni = 0; ni < 2; ++ni) {
      int col = i0 + wv * 32 + ni * 16 + fr;
#pragma unroll
      for (int e = 0; e < 4; ++e) {
        int bb = mi * 16 + q * 4 + e;
        pout[(size_t)bb * D + col] = R[mi][ni][e];
      }
    }
}

// ---------------------------------------------------------------------------
// K3R: u_slots[b,s,i] = (sum_sp part[sp,s,b,i]) / weighted_c[b,s]
// ---------------------------------------------------------------------------
__global__ __launch_bounds__(256) void k3r_reduce(
    const float* __restrict__ part, const float* __restrict__ wc,
    float* __restrict__ u_slots, int nsplit) {
  int idx = blockIdx.x * 256 + threadIdx.x;  // over (s,b,i)
  int i  = idx & (D - 1);
  int sb = idx >> 8;
  int b  = sb & (B - 1);
  int s  = sb >> 7;
  float v = 0.f;
  for (int sp = 0; sp < nsplit; ++sp)
    v += part[(size_t)sp * (NS * B * D) + idx];
  u_slots[((size_t)b * NS + s) * D + i] = v / wc[b * NS + s];
}

// ---------------------------------------------------------------------------
// K4: per (b,s): logits2 = w_route_si[s] . u_slots[b,s]; softmax over NI;
//     w2 = c_si * a_slots.
// ---------------------------------------------------------------------------
__global__ __launch_bounds__(64) void k4_route_si(
    const float* __restrict__ u_slots, const float* __restrict__ wr_si,
    const float* __restrict__ a_slots, float* __restrict__ w2) {
  int bs = blockIdx.x;
  int s  = bs & (NS - 1);
  int lane = threadIdx.x;
  __shared__ float su[D];
  __shared__ float slog[NI];
#pragma unroll
  for (int jj = 0; jj < 4; ++jj) su[lane + jj * 64] = u_slots[bs * D + lane + jj * 64];
  __syncthreads();
  for (int i = 0; i < NI; ++i) {
    const float* w = wr_si + (s * NI + i) * D;
    float p = 0.f;
#pragma unroll
    for (int jj = 0; jj < 4; ++jj) {
      int j = lane + jj * 64;
      p = fmaf(w[j], su[j], p);
    }
    p = wave_reduce_sum(p);
    if (lane == 0) slog[i] = p;
  }
  __syncthreads();
  float v = (lane < NI) ? slog[lane] : -INFINITY;
  float m = wave_reduce_max(v);
  float e = (lane < NI) ? __expf(v - m) : 0.f;
  float ssum = wave_reduce_sum(e);
  if (lane < NI) w2[bs * NI + lane] = (e / ssum) * a_slots[bs];
}

// ---------------------------------------------------------------------------
// K5: wc2[b,i] = sum_s w2; a_intents = wc2 / sum_s a_slots.
// ---------------------------------------------------------------------------
__global__ __launch_bounds__(64) void k5_intents_agg(
    const float* __restrict__ w2, const float* __restrict__ a_slots,
    float* __restrict__ wc2, float* __restrict__ a_intents) {
  int b = blockIdx.x;
  int lane = threadIdx.x;
  float as = (lane < NS) ? a_slots[b * NS + lane] : 0.f;
  float sas = wave_reduce_sum(as);
  if (lane < NI) {
    float wc = 0.f;
    for (int s = 0; s < NS; ++s) wc += w2[(b * NS + s) * NI + lane];
    wc2[b * NI + lane] = wc;
    a_intents[b * NI + lane] = wc / sas;
  }
}

// ---------------------------------------------------------------------------
// K6: Wsum[s,i,k] = sum_j w_pose_si[s,i,j,k] (float4-vectorized over k).
// ---------------------------------------------------------------------------
__global__ __launch_bounds__(256) void k6_wsum(
    const float* __restrict__ wps, float* __restrict__ wsum) {
  __shared__ float red[4][D];
  int si = blockIdx.x;
  int t  = threadIdx.x;
  int k4 = (t & 63) * 4;
  int jg = t >> 6;
  const float* base = wps + (size_t)si * D * D;
  float4 acc = {0.f, 0.f, 0.f, 0.f};
  for (int j = jg; j < D; j += 4) {
    float4 v = *(const float4*)(base + (size_t)j * D + k4);
    acc.x += v.x; acc.y += v.y; acc.z += v.z; acc.w += v.w;
  }
  *(float4*)&red[jg][k4] = acc;
  __syncthreads();
  wsum[si * D + t] = (red[0][t] + red[1][t]) + (red[2][t] + red[3][t]);
}

// ---------------------------------------------------------------------------
// K7: u_intents[b,i,k] = sum_s w2[b,s,i]*u_slots[b,s,k]*Wsum[s,i,k] / wc2[b,i]
// ---------------------------------------------------------------------------
__global__ __launch_bounds__(256) void k7_uintents(
    const float* __restrict__ u_slots, const float* __restrict__ w2,
    const float* __restrict__ wsum, const float* __restrict__ wc2,
    float* __restrict__ u_intents) {
  int bi = blockIdx.x;
  int b = bi >> 4, i = bi & (NI - 1);
  int k = threadIdx.x;
  float acc = 0.f;
  for (int s = 0; s < NS; ++s) {
    float w = w2[(b * NS + s) * NI + i];
    acc = fmaf(w * u_slots[(b * NS + s) * D + k], wsum[(s * NI + i) * D + k], acc);
  }
  u_intents[bi * D + k] = acc / wc2[bi];
}

// ---------------------------------------------------------------------------
extern "C" void kernel_launch(void* const* d_in, const int* in_sizes, int n_in,
                              void* d_out, int out_size, void* d_ws, size_t ws_size,
                              hipStream_t stream) {
  const float* tf    = (const float*)d_in[0];  // (B,L,D)
  const float* wr_ws = (const float*)d_in[1];  // (L,NS,D)
  const float* wp_ws = (const float*)d_in[2];  // (L,NS,D,D)
  const float* wr_si = (const float*)d_in[3];  // (NS,NI,D)
  const float* wp_si = (const float*)d_in[4];  // (NS,NI,D,D)

  float* out       = (float*)d_out;
  float* a_slots   = out;                      // B*NS
  float* u_slots   = a_slots + B * NS;         // B*NS*D
  float* a_intents = u_slots + B * NS * D;     // B*NI
  float* u_intents = a_intents + B * NI;       // B*NI*D

  float* ws         = (float*)d_ws;
  float* wlsT       = ws;                      // L*NS*B  = 262144
  float* a_words    = wlsT + L * NS * B;       // B*L     = 8192
  float* weighted_c = a_words + B * L;         // B*NS    = 4096
  float* w2         = weighted_c + B * NS;     // B*NS*NI = 65536
  float* wc2        = w2 + B * NS * NI;        // B*NI    = 2048
  float* wsum       = wc2 + B * NI;            // NS*NI*D = 131072
  // bf16 hi/lo swizzled images of tf: 512 tiles x 4096 ushorts each
  ushort* xh        = (ushort*)(wsum + NS * NI * D);       // 2,097,152 ushorts
  ushort* xl        = xh + (size_t)L * 8 * 4096;           // 2,097,152 ushorts
  float*  part      = (float*)(xl + (size_t)L * 8 * 4096); // nsplit*NS*B*D

  const size_t base_f  = 473088 + 2097152;     // floats incl. images
  const size_t chunk_f = (size_t)NS * B * D;   // 1,048,576 per split
  size_t avail_f = ws_size / sizeof(float);
  int nsplit = 1;
  if (avail_f >= base_f + 8 * chunk_f)      nsplit = 8;
  else if (avail_f >= base_f + 4 * chunk_f) nsplit = 4;
  else if (avail_f >= base_f + 2 * chunk_f) nsplit = 2;

  kx_split<<<L * 4, 256, 0, stream>>>(tf, xh, xl);
  k1_route_words<<<B * L, 256, 0, stream>>>(tf, wr_ws, wlsT, a_words);
  k2_slots_agg<<<B, 64, 0, stream>>>(wlsT, a_words, weighted_c, a_slots);
  // grid: (s x ihalf) x nsplit; bx%nsplit = sp -> same-sp on same XCD
  k3_mfma<<<NS * 2 * nsplit, 256, 0, stream>>>(xh, xl, wp_ws, wlsT, part, nsplit);
  k3r_reduce<<<(NS * B * D) / 256, 256, 0, stream>>>(part, weighted_c, u_slots, nsplit);
  k6_wsum<<<NS * NI, 256, 0, stream>>>(wp_si, wsum);
  k4_route_si<<<B * NS, 64, 0, stream>>>(u_slots, wr_si, a_slots, w2);
  k5_intents_agg<<<B, 64, 0, stream>>>(w2, a_slots, wc2, a_intents);
  k7_uintents<<<B * NI, 256, 0, stream>>>(u_slots, w2, wsum, wc2, u_intents);
}